// Round 3
// baseline (299.713 us; speedup 1.0000x reference)
//
#include <hip/hip_runtime.h>

// expRNN/modReLU recurrence, B=8192, T=784, I=1, H=30, C=10.
//
// Round 8 = R5 (213us, best measured) + ONLY two changes:
//   - x via float2 ds_read_b64 once per 2 steps, TRIPLE-buffered (xq/xn/xf,
//     prefetch 2 iters ahead): even a scheduler-sunk load has >=1 full body
//     (~800 cyc) before first use -> ds latency (~120 cyc) never exposed.
//     (R6/R7 proved the x-feed/branch stall is real: their stall dropped
//     190->117 cyc/step; but their clustered-q STEP grew the live set and
//     added ~200 busy cyc/step of AGPR shuttle movs. R8 keeps R5's
//     just-in-time SSTEP structure: live set grows by only 4 regs.)
//   - t-loop unrolled x2 (392 iters): branch bubble halved.
// Predict: busy ~462 cyc/step (unchanged), stall 190 -> ~60-90,
// dur 175-195 us, VGPR 104-110, VALUBusy 75-82%.

#define T_STEPS 784
#define NBATCH  8192
#define NH      30
#define NC      10
#define BPB     8     // batches per block
#define XPAD    788   // padded x row: 788%2==0 (float2 LDS, 8B-aligned rows)
                      // and 788%32==20 -> 8 batch rows hit distinct banks

// lane receives value from lane (w - 2S) & 15 within its 16-lane row
#define ROR2(dst, src, S) \
    dst = __int_as_float(__builtin_amdgcn_update_dpp( \
        0, __float_as_int(src), 0x120 + 2*(S), 0xf, 0xf, true))

#define PIN8(a,b,c,d,e,f,g,h) \
    asm volatile("" : "+v"(a),"+v"(b),"+v"(c),"+v"(d), \
                      "+v"(e),"+v"(f),"+v"(g),"+v"(h))

typedef float v2f __attribute__((ext_vector_type(2)));

__global__ __launch_bounds__(64, 1)
void rnn_modrelu_l8(const float* __restrict__ inp,    // [B, T, 1]
                    const float* __restrict__ W_ih,   // [H, 1]
                    const float* __restrict__ W_hh,   // [H, H]
                    const float* __restrict__ b_mod,  // [H]
                    const float* __restrict__ W_lin,  // [C, H]
                    const float* __restrict__ b_lin,  // [C]
                    float* __restrict__ out)          // [B, C]
{
    __shared__ __align__(16) float xl[BPB * XPAD];   // 25.2 KB
    __shared__ __align__(16) float wl[NH * NH];      // 3.6 KB
    __shared__ float hfin[BPB * 32];

    const int l     = threadIdx.x;
    const int blk   = blockIdx.x;
    const int w16   = l & 15;
    const int row16 = l >> 4;
    const int u     = w16 >> 1;          // 8-lane sub-index (chunk owner)
    const int bl    = 2 * row16 + (w16 & 1);  // local batch 0..7

    // ---- preload x (8 batches x 784), padded rows, coalesced float4 ----
    {
        const float4* src = (const float4*)(inp + (size_t)blk * (BPB * T_STEPS));
        #pragma unroll
        for (int k = 0; k < 25; ++k) {
            int v = l + 64 * k;                 // float4 index, < 1568
            if (v < (BPB * T_STEPS) / 4) {
                int b   = v / 196;              // 196 float4 per batch row
                int rem = v - b * 196;
                *(float4*)(xl + b * XPAD + 4 * rem) = src[v];
            }
        }
    }
    // ---- stage W_hh to LDS (coalesced) ----
    {
        const float4* src = (const float4*)W_hh;
        #pragma unroll
        for (int k = 0; k < 4; ++k) {
            int idx = l + 64 * k;
            if (idx < (NH * NH) / 4) ((float4*)wl)[idx] = src[idx];
        }
    }
    __syncthreads();

    // ---- per-lane pre-rotated W: step s consumes chunk c=(u-s)&7 ----
    const int r0 = 4 * u;                // first owned row
    float wq[8][4][4];
    #pragma unroll
    for (int s = 0; s < 8; ++s) {
        const int c = (u - s) & 7;
        #pragma unroll
        for (int r = 0; r < 4; ++r) {
            const int row = r0 + r;
            #pragma unroll
            for (int j = 0; j < 4; ++j) {
                const int col = 4 * c + j;
                wq[s][r][j] = (row < NH && col < NH) ? wl[row * NH + col] : 0.0f;
            }
        }
    }
    float wih[4], bm[4];
    #pragma unroll
    for (int r = 0; r < 4; ++r) {
        const int row = r0 + r;
        wih[r] = (row < NH) ? W_ih[row]  : 0.0f;
        bm[r]  = (row < NH) ? b_mod[row] : 0.0f;
    }
    // pin W in VGPRs (pre-loop only)
    #pragma unroll
    for (int s = 0; s < 8; ++s) {
        PIN8(wq[s][0][0], wq[s][0][1], wq[s][0][2], wq[s][0][3],
             wq[s][1][0], wq[s][1][1], wq[s][1][2], wq[s][1][3]);
        PIN8(wq[s][2][0], wq[s][2][1], wq[s][2][2], wq[s][2][3],
             wq[s][3][0], wq[s][3][1], wq[s][3][2], wq[s][3][3]);
    }

    float h0 = 0.0f, h1 = 0.0f, h2 = 0.0f, h3 = 0.0f;  // own rows r0..r0+3

    #define SSTEP(S) { \
        float q0, q1, q2, q3; \
        ROR2(q0, h0, S); ROR2(q1, h1, S); ROR2(q2, h2, S); ROR2(q3, h3, S); \
        z0 = fmaf(wq[S][0][0], q0, z0); z1 = fmaf(wq[S][1][0], q0, z1); \
        z2 = fmaf(wq[S][2][0], q0, z2); z3 = fmaf(wq[S][3][0], q0, z3); \
        z0 = fmaf(wq[S][0][1], q1, z0); z1 = fmaf(wq[S][1][1], q1, z1); \
        z2 = fmaf(wq[S][2][1], q1, z2); z3 = fmaf(wq[S][3][1], q1, z3); \
        z0 = fmaf(wq[S][0][2], q2, z0); z1 = fmaf(wq[S][1][2], q2, z1); \
        z2 = fmaf(wq[S][2][2], q2, z2); z3 = fmaf(wq[S][3][2], q2, z3); \
        z0 = fmaf(wq[S][0][3], q3, z0); z1 = fmaf(wq[S][1][3], q3, z1); \
        z2 = fmaf(wq[S][2][3], q3, z2); z3 = fmaf(wq[S][3][3], q3, z3); \
    }

    #define STEP(XV) { \
        float z0 = wih[0] * (XV); \
        float z1 = wih[1] * (XV); \
        float z2 = wih[2] * (XV); \
        float z3 = wih[3] * (XV); \
        /* s = 0: own chunk */ \
        _Pragma("unroll") \
        for (int j = 0; j < 4; ++j) { \
            const float qh = (j == 0) ? h0 : (j == 1) ? h1 : (j == 2) ? h2 : h3; \
            z0 = fmaf(wq[0][0][j], qh, z0); \
            z1 = fmaf(wq[0][1][j], qh, z1); \
            z2 = fmaf(wq[0][2][j], qh, z2); \
            z3 = fmaf(wq[0][3][j], qh, z3); \
        } \
        SSTEP(1) SSTEP(2) SSTEP(3) SSTEP(4) SSTEP(5) SSTEP(6) SSTEP(7) \
        h0 = copysignf(fmaxf(fabsf(z0) + bm[0], 0.0f), z0); \
        h1 = copysignf(fmaxf(fabsf(z1) + bm[1], 0.0f), z1); \
        h2 = copysignf(fmaxf(fabsf(z2) + bm[2], 0.0f), z2); \
        h3 = copysignf(fmaxf(fabsf(z3) + bm[3], 0.0f), z3); \
    }

    // ---- main recurrence: 392 outer iters x 2 steps ----
    // x triple-buffered: load for iter m+2 issued in iter m.
    const v2f* xv2 = (const v2f*)(xl + bl * XPAD);
    v2f xq = xv2[0];
    v2f xn = xv2[1];
    #pragma unroll 1
    for (int m = 0; m < 392; ++m) {
        // max index: 391+2=393 -> floats 786,787 < 788 (padded, in-bounds;
        // values discarded after the final iterations).
        v2f xf = xv2[m + 2];

        STEP(xq.x);
        STEP(xq.y);

        xq = xn;
        xn = xf;
    }
    #undef STEP
    #undef SSTEP

    // ---- stash h for classifier ----
    hfin[bl * 32 + r0 + 0] = h0;
    hfin[bl * 32 + r0 + 1] = h1;
    hfin[bl * 32 + r0 + 2] = h2;
    hfin[bl * 32 + r0 + 3] = h3;
    __syncthreads();

    // ---- classifier: 80 outputs (8 batches x 10 classes) ----
    #pragma unroll
    for (int it = 0; it < 2; ++it) {
        const int k = l + 64 * it;
        if (k < BPB * NC) {
            const int bbo = k / NC;
            const int c   = k % NC;
            float acc = b_lin[c];
            #pragma unroll
            for (int i = 0; i < NH; ++i) {
                acc = fmaf(W_lin[c * NH + i], hfin[bbo * 32 + i], acc);
            }
            out[((size_t)blk * BPB + bbo) * NC + c] = acc;
        }
    }
}

extern "C" void kernel_launch(void* const* d_in, const int* in_sizes, int n_in,
                              void* d_out, int out_size, void* d_ws, size_t ws_size,
                              hipStream_t stream) {
    const float* inp   = (const float*)d_in[0];
    const float* W_ih  = (const float*)d_in[1];
    const float* W_hh  = (const float*)d_in[2];
    const float* b_mod = (const float*)d_in[3];
    const float* W_lin = (const float*)d_in[4];
    const float* b_lin = (const float*)d_in[5];
    float* out = (float*)d_out;

    dim3 grid(NBATCH / BPB);   // 1024 blocks
    dim3 block(64);            // one wave
    rnn_modrelu_l8<<<grid, block, 0, stream>>>(inp, W_ih, W_hh, b_mod,
                                               W_lin, b_lin, out);
}